// Round 1
// baseline (2911.694 us; speedup 1.0000x reference)
//
#include <hip/hip_runtime.h>

#define BN_EPS 1e-5f

// -------- Edge scatter: agg[dst] += relu(x[src] + edge_attr), fp32 atomics --------
__global__ void edge_kernel(const float* __restrict__ x, const int* __restrict__ ei,
                            const float* __restrict__ ea, float* __restrict__ agg, int E) {
    int i = blockIdx.x * blockDim.x + threadIdx.x;
    const int stride = gridDim.x * blockDim.x;
    const int total = E * 32;          // 32 float4-chunks... actually 32 chunks of 4 floats = 128
    for (; i < total; i += stride) {
        const int e = i >> 5;
        const int c = i & 31;
        const int src = ei[e];
        const int dst = ei[E + e];
        const float4 xv = ((const float4*)(x + (size_t)src * 128))[c];
        const float4 ev = ((const float4*)(ea + (size_t)e * 128))[c];
        float* op = agg + (size_t)dst * 128 + c * 4;
        unsafeAtomicAdd(op + 0, fmaxf(xv.x + ev.x, 0.f));
        unsafeAtomicAdd(op + 1, fmaxf(xv.y + ev.y, 0.f));
        unsafeAtomicAdd(op + 2, fmaxf(xv.z + ev.z, 0.f));
        unsafeAtomicAdd(op + 3, fmaxf(xv.w + ev.w, 0.f));
    }
}

// -------- MLP: h2 = relu((x+agg)@W1+b1)@W2+b2 ; fused BN-stat accumulation --------
__launch_bounds__(256, 1)
__global__ void mlp_kernel(const float* __restrict__ x, const float* __restrict__ agg,
                           const float* __restrict__ W1, const float* __restrict__ b1,
                           const float* __restrict__ W2, const float* __restrict__ b2,
                           float* __restrict__ out, double* __restrict__ stats, int N) {
    __shared__ float Xs[128 * 129];   // 128 nodes x 128 cols, pad 129 (conflict-free col reads)
    __shared__ float Ws[64 * 128];    // half of a weight matrix
    const int tid = threadIdx.x;
    const int gn = tid >> 4;          // node group 0..15 (8 nodes each)
    const int gc = tid & 15;          // col group 0..15 (8 cols each)
    const int base = blockIdx.x * 128;

    // Load X tile = x + agg (2 threads per row, 64 cols each)
    {
        const int r = tid >> 1;
        const int c0 = (tid & 1) * 64;
        const int n = base + r;
        float* xrow = &Xs[r * 129 + c0];
        if (n < N) {
            const float4* sx = (const float4*)(x + (size_t)n * 128 + c0);
            const float4* sa = (const float4*)(agg + (size_t)n * 128 + c0);
            #pragma unroll
            for (int q = 0; q < 16; q++) {
                float4 v = sx[q], a = sa[q];
                xrow[q*4+0] = v.x + a.x; xrow[q*4+1] = v.y + a.y;
                xrow[q*4+2] = v.z + a.z; xrow[q*4+3] = v.w + a.w;
            }
        } else {
            #pragma unroll
            for (int q = 0; q < 64; q++) xrow[q] = 0.f;
        }
    }

    float acc[8][8];
    #pragma unroll
    for (int i = 0; i < 8; i++)
        #pragma unroll
        for (int j = 0; j < 8; j++) acc[i][j] = 0.f;

    // ---- Layer 1 ----
    for (int half = 0; half < 2; half++) {
        __syncthreads();                       // previous Ws use done (and Xs load @half 0)
        {
            const float4* w4 = (const float4*)(W1 + half * 64 * 128);
            float4* ws4 = (float4*)Ws;
            #pragma unroll
            for (int q = 0; q < 8; q++) ws4[tid + 256 * q] = w4[tid + 256 * q];
        }
        __syncthreads();
        for (int k = 0; k < 64; k++) {
            const int kk = half * 64 + k;
            float xv[8];
            #pragma unroll
            for (int i = 0; i < 8; i++) xv[i] = Xs[(gn*8+i)*129 + kk];
            const float4 wa = *(const float4*)&Ws[k*128 + gc*8];
            const float4 wb = *(const float4*)&Ws[k*128 + gc*8 + 4];
            const float wv[8] = {wa.x, wa.y, wa.z, wa.w, wb.x, wb.y, wb.z, wb.w};
            #pragma unroll
            for (int i = 0; i < 8; i++)
                #pragma unroll
                for (int j = 0; j < 8; j++)
                    acc[i][j] = fmaf(xv[i], wv[j], acc[i][j]);
        }
    }

    // bias + relu -> write h1 back into Xs
    float bv[8];
    #pragma unroll
    for (int j = 0; j < 8; j++) bv[j] = b1[gc*8 + j];
    __syncthreads();                           // everyone done reading Xs (and Ws)
    #pragma unroll
    for (int i = 0; i < 8; i++)
        #pragma unroll
        for (int j = 0; j < 8; j++)
            Xs[(gn*8+i)*129 + gc*8 + j] = fmaxf(acc[i][j] + bv[j], 0.f);

    #pragma unroll
    for (int i = 0; i < 8; i++)
        #pragma unroll
        for (int j = 0; j < 8; j++) acc[i][j] = 0.f;

    // ---- Layer 2 ----
    for (int half = 0; half < 2; half++) {
        __syncthreads();                       // h1 writeback visible / previous Ws use done
        {
            const float4* w4 = (const float4*)(W2 + half * 64 * 128);
            float4* ws4 = (float4*)Ws;
            #pragma unroll
            for (int q = 0; q < 8; q++) ws4[tid + 256 * q] = w4[tid + 256 * q];
        }
        __syncthreads();
        for (int k = 0; k < 64; k++) {
            const int kk = half * 64 + k;
            float xv[8];
            #pragma unroll
            for (int i = 0; i < 8; i++) xv[i] = Xs[(gn*8+i)*129 + kk];
            const float4 wa = *(const float4*)&Ws[k*128 + gc*8];
            const float4 wb = *(const float4*)&Ws[k*128 + gc*8 + 4];
            const float wv[8] = {wa.x, wa.y, wa.z, wa.w, wb.x, wb.y, wb.z, wb.w};
            #pragma unroll
            for (int i = 0; i < 8; i++)
                #pragma unroll
                for (int j = 0; j < 8; j++)
                    acc[i][j] = fmaf(xv[i], wv[j], acc[i][j]);
        }
    }

    #pragma unroll
    for (int j = 0; j < 8; j++) bv[j] = b2[gc*8 + j];

    // store h2 + accumulate per-column sum / sumsq (valid nodes only)
    float s[8], q[8];
    #pragma unroll
    for (int j = 0; j < 8; j++) { s[j] = 0.f; q[j] = 0.f; }
    #pragma unroll
    for (int i = 0; i < 8; i++) {
        const int n = base + gn*8 + i;
        if (n < N) {
            float h2[8];
            #pragma unroll
            for (int j = 0; j < 8; j++) h2[j] = acc[i][j] + bv[j];
            float4 va = {h2[0], h2[1], h2[2], h2[3]};
            float4 vb = {h2[4], h2[5], h2[6], h2[7]};
            float* op = out + (size_t)n * 128 + gc*8;
            *(float4*)op = va;
            *(float4*)(op + 4) = vb;
            #pragma unroll
            for (int j = 0; j < 8; j++) { s[j] += h2[j]; q[j] += h2[j]*h2[j]; }
        }
    }

    __syncthreads();                           // Ws free for reduction scratch
    float* RedS = Ws;                          // [16][128]
    float* RedQ = Ws + 2048;                   // [16][128]
    #pragma unroll
    for (int j = 0; j < 8; j++) {
        RedS[gn*128 + gc*8 + j] = s[j];
        RedQ[gn*128 + gc*8 + j] = q[j];
    }
    __syncthreads();
    if (tid < 128) {
        float ss = 0.f, qq = 0.f;
        #pragma unroll
        for (int g = 0; g < 16; g++) { ss += RedS[g*128 + tid]; qq += RedQ[g*128 + tid]; }
        unsafeAtomicAdd(&stats[tid], (double)ss);
        unsafeAtomicAdd(&stats[128 + tid], (double)qq);
    }
}

// -------- BN prep: per-column scale/bias from sums --------
__global__ void bnprep_kernel(const double* __restrict__ stats, const float* __restrict__ gamma,
                              const float* __restrict__ beta, float* __restrict__ sb, float invN) {
    const int c = threadIdx.x;   // 128
    const float mean = (float)(stats[c] * (double)invN);
    const float ex2  = (float)(stats[128 + c] * (double)invN);
    const float var  = ex2 - mean * mean;
    const float rstd = rsqrtf(var + BN_EPS);
    const float sc = rstd * gamma[c];
    sb[c] = sc;
    sb[128 + c] = beta[c] - mean * sc;
}

// -------- BN apply + final relu, in-place on d_out --------
__global__ void bn_kernel(float4* __restrict__ out4, const float* __restrict__ sb, int n4) {
    int i = blockIdx.x * blockDim.x + threadIdx.x;
    const int stride = gridDim.x * blockDim.x;
    for (; i < n4; i += stride) {
        const int c4 = (i & 31) << 2;
        float4 v = out4[i];
        const float4 sc = *(const float4*)&sb[c4];
        const float4 bs = *(const float4*)&sb[128 + c4];
        v.x = fmaxf(fmaf(v.x, sc.x, bs.x), 0.f);
        v.y = fmaxf(fmaf(v.y, sc.y, bs.y), 0.f);
        v.z = fmaxf(fmaf(v.z, sc.z, bs.z), 0.f);
        v.w = fmaxf(fmaf(v.w, sc.w, bs.w), 0.f);
        out4[i] = v;
    }
}

extern "C" void kernel_launch(void* const* d_in, const int* in_sizes, int n_in,
                              void* d_out, int out_size, void* d_ws, size_t ws_size,
                              hipStream_t stream) {
    const float* x     = (const float*)d_in[0];
    const int*   ei    = (const int*)d_in[1];
    const float* ea    = (const float*)d_in[2];
    const float* W1    = (const float*)d_in[3];
    const float* b1    = (const float*)d_in[4];
    const float* W2    = (const float*)d_in[5];
    const float* b2    = (const float*)d_in[6];
    const float* gamma = (const float*)d_in[7];
    const float* beta  = (const float*)d_in[8];
    float* out = (float*)d_out;

    const int N = in_sizes[0] / 128;
    const int E = in_sizes[1] / 2;

    const size_t aggBytes = (size_t)N * 128 * sizeof(float);
    float*  agg   = (float*)d_ws;
    double* stats = (double*)((char*)d_ws + aggBytes);            // 256 doubles
    float*  sb    = (float*)((char*)d_ws + aggBytes + 256 * 8);   // 256 floats

    // zero agg + stats
    hipMemsetAsync(d_ws, 0, aggBytes + 256 * 8, stream);

    edge_kernel<<<4096, 256, 0, stream>>>(x, ei, ea, agg, E);

    mlp_kernel<<<(N + 127) / 128, 256, 0, stream>>>(x, agg, W1, b1, W2, b2, out, stats, N);

    bnprep_kernel<<<1, 128, 0, stream>>>(stats, gamma, beta, sb, 1.0f / (float)N);

    const int n4 = N * 32;
    bn_kernel<<<2048, 256, 0, stream>>>((float4*)out, sb, n4);
}

// Round 2
// 616.430 us; speedup vs baseline: 4.7235x; 4.7235x over previous
//
#include <hip/hip_runtime.h>

#define BN_EPS 1e-5f

// ================= CSR build: counting sort of edges by dst =================

__global__ void count_kernel(const int* __restrict__ ei, int* __restrict__ deg, int E) {
    int i = blockIdx.x * blockDim.x + threadIdx.x;
    const int stride = gridDim.x * blockDim.x;
    for (; i < E; i += stride) atomicAdd(&deg[ei[E + i]], 1);
}

// block-level exclusive scan: 1024 elems/block (256 thr x 4)
__global__ void scanA(const int* __restrict__ deg, int* __restrict__ rowStart,
                      int* __restrict__ blockSums, int N) {
    __shared__ int sd[256];
    const int t = threadIdx.x;
    const int idx = blockIdx.x * 1024 + t * 4;
    int d0 = 0, d1 = 0, d2 = 0, d3 = 0;
    if (idx + 3 < N) { int4 v = *(const int4*)&deg[idx]; d0 = v.x; d1 = v.y; d2 = v.z; d3 = v.w; }
    else {
        if (idx     < N) d0 = deg[idx];
        if (idx + 1 < N) d1 = deg[idx + 1];
        if (idx + 2 < N) d2 = deg[idx + 2];
    }
    const int s = d0 + d1 + d2 + d3;
    sd[t] = s;
    __syncthreads();
    #pragma unroll
    for (int off = 1; off < 256; off <<= 1) {
        const int v = (t >= off) ? sd[t - off] : 0;
        __syncthreads();
        sd[t] += v;
        __syncthreads();
    }
    const int ex = sd[t] - s;
    if (idx     < N) rowStart[idx]     = ex;
    if (idx + 1 < N) rowStart[idx + 1] = ex + d0;
    if (idx + 2 < N) rowStart[idx + 2] = ex + d0 + d1;
    if (idx + 3 < N) rowStart[idx + 3] = ex + d0 + d1 + d2;
    if (t == 255) blockSums[blockIdx.x] = sd[255];
}

// exclusive scan of per-block sums (nblk <= 256)
__global__ void scanB(int* __restrict__ blockSums, int nblk) {
    __shared__ int sd[256];
    const int t = threadIdx.x;
    const int s = (t < nblk) ? blockSums[t] : 0;
    sd[t] = s;
    __syncthreads();
    #pragma unroll
    for (int off = 1; off < 256; off <<= 1) {
        const int v = (t >= off) ? sd[t - off] : 0;
        __syncthreads();
        sd[t] += v;
        __syncthreads();
    }
    if (t < nblk) blockSums[t] = sd[t] - s;
}

__global__ void scanC(int* __restrict__ rowStart, int* __restrict__ cursor,
                      const int* __restrict__ blockSums, int N) {
    int i = blockIdx.x * blockDim.x + threadIdx.x;
    const int stride = gridDim.x * blockDim.x;
    for (; i < N; i += stride) {
        const int v = rowStart[i] + blockSums[i >> 10];
        rowStart[i] = v;
        cursor[i]   = v;
    }
}

__global__ void scatter_kernel(const int* __restrict__ ei, int* __restrict__ cursor,
                               int* __restrict__ sEid, int* __restrict__ sSrc, int E) {
    int i = blockIdx.x * blockDim.x + threadIdx.x;
    const int stride = gridDim.x * blockDim.x;
    for (; i < E; i += stride) {
        const int dst = ei[E + i];
        const int pos = atomicAdd(&cursor[dst], 1);
        sEid[pos] = i;
        sSrc[pos] = ei[i];
    }
}

// ============ Gather-aggregate: h0[n] = x[n] + sum relu(x[src]+ea[e]) ============
// one wave per node; lane holds float2 of the 128-wide row
__global__ void agg_kernel(const float* __restrict__ x, const float* __restrict__ ea,
                           const int* __restrict__ sEid, const int* __restrict__ sSrc,
                           const int* __restrict__ rowStart, const int* __restrict__ deg,
                           float* __restrict__ h0, int N) {
    const int wid = (blockIdx.x * blockDim.x + threadIdx.x) >> 6;
    if (wid >= N) return;
    const int lane = threadIdx.x & 63;
    float2 acc = ((const float2*)(x + (size_t)wid * 128))[lane];
    const int rs = rowStart[wid];
    const int end = rs + deg[wid];
    int j = rs;
    for (; j + 2 <= end; j += 2) {
        const int e0 = sEid[j],     s0 = sSrc[j];
        const int e1 = sEid[j + 1], s1 = sSrc[j + 1];
        const float2 a0 = ((const float2*)(ea + (size_t)e0 * 128))[lane];
        const float2 x0 = ((const float2*)(x  + (size_t)s0 * 128))[lane];
        const float2 a1 = ((const float2*)(ea + (size_t)e1 * 128))[lane];
        const float2 x1 = ((const float2*)(x  + (size_t)s1 * 128))[lane];
        acc.x += fmaxf(a0.x + x0.x, 0.f) + fmaxf(a1.x + x1.x, 0.f);
        acc.y += fmaxf(a0.y + x0.y, 0.f) + fmaxf(a1.y + x1.y, 0.f);
    }
    if (j < end) {
        const int e0 = sEid[j], s0 = sSrc[j];
        const float2 a0 = ((const float2*)(ea + (size_t)e0 * 128))[lane];
        const float2 x0 = ((const float2*)(x  + (size_t)s0 * 128))[lane];
        acc.x += fmaxf(a0.x + x0.x, 0.f);
        acc.y += fmaxf(a0.y + x0.y, 0.f);
    }
    ((float2*)(h0 + (size_t)wid * 128))[lane] = acc;
}

// ===== MLP: h2 = relu(h0@W1+b1)@W2+b2 (in-place on d_out) + BN stats =====
__launch_bounds__(256, 1)
__global__ void mlp_kernel(const float* __restrict__ h0,
                           const float* __restrict__ W1, const float* __restrict__ b1,
                           const float* __restrict__ W2, const float* __restrict__ b2,
                           float* __restrict__ out, double* __restrict__ stats, int N) {
    __shared__ float Xs[128 * 129];
    __shared__ float Ws[64 * 128];
    const int tid = threadIdx.x;
    const int gn = tid >> 4;
    const int gc = tid & 15;
    const int base = blockIdx.x * 128;

    {
        const int r = tid >> 1;
        const int c0 = (tid & 1) * 64;
        const int n = base + r;
        float* xrow = &Xs[r * 129 + c0];
        if (n < N) {
            const float4* sh = (const float4*)(h0 + (size_t)n * 128 + c0);
            #pragma unroll
            for (int q = 0; q < 16; q++) {
                float4 v = sh[q];
                xrow[q*4+0] = v.x; xrow[q*4+1] = v.y;
                xrow[q*4+2] = v.z; xrow[q*4+3] = v.w;
            }
        } else {
            #pragma unroll
            for (int q = 0; q < 64; q++) xrow[q] = 0.f;
        }
    }

    float acc[8][8];
    #pragma unroll
    for (int i = 0; i < 8; i++)
        #pragma unroll
        for (int j = 0; j < 8; j++) acc[i][j] = 0.f;

    for (int half = 0; half < 2; half++) {
        __syncthreads();
        {
            const float4* w4 = (const float4*)(W1 + half * 64 * 128);
            float4* ws4 = (float4*)Ws;
            #pragma unroll
            for (int q = 0; q < 8; q++) ws4[tid + 256 * q] = w4[tid + 256 * q];
        }
        __syncthreads();
        for (int k = 0; k < 64; k++) {
            const int kk = half * 64 + k;
            float xv[8];
            #pragma unroll
            for (int i = 0; i < 8; i++) xv[i] = Xs[(gn*8+i)*129 + kk];
            const float4 wa = *(const float4*)&Ws[k*128 + gc*8];
            const float4 wb = *(const float4*)&Ws[k*128 + gc*8 + 4];
            const float wv[8] = {wa.x, wa.y, wa.z, wa.w, wb.x, wb.y, wb.z, wb.w};
            #pragma unroll
            for (int i = 0; i < 8; i++)
                #pragma unroll
                for (int j = 0; j < 8; j++)
                    acc[i][j] = fmaf(xv[i], wv[j], acc[i][j]);
        }
    }

    float bv[8];
    #pragma unroll
    for (int j = 0; j < 8; j++) bv[j] = b1[gc*8 + j];
    __syncthreads();
    #pragma unroll
    for (int i = 0; i < 8; i++)
        #pragma unroll
        for (int j = 0; j < 8; j++)
            Xs[(gn*8+i)*129 + gc*8 + j] = fmaxf(acc[i][j] + bv[j], 0.f);

    #pragma unroll
    for (int i = 0; i < 8; i++)
        #pragma unroll
        for (int j = 0; j < 8; j++) acc[i][j] = 0.f;

    for (int half = 0; half < 2; half++) {
        __syncthreads();
        {
            const float4* w4 = (const float4*)(W2 + half * 64 * 128);
            float4* ws4 = (float4*)Ws;
            #pragma unroll
            for (int q = 0; q < 8; q++) ws4[tid + 256 * q] = w4[tid + 256 * q];
        }
        __syncthreads();
        for (int k = 0; k < 64; k++) {
            const int kk = half * 64 + k;
            float xv[8];
            #pragma unroll
            for (int i = 0; i < 8; i++) xv[i] = Xs[(gn*8+i)*129 + kk];
            const float4 wa = *(const float4*)&Ws[k*128 + gc*8];
            const float4 wb = *(const float4*)&Ws[k*128 + gc*8 + 4];
            const float wv[8] = {wa.x, wa.y, wa.z, wa.w, wb.x, wb.y, wb.z, wb.w};
            #pragma unroll
            for (int i = 0; i < 8; i++)
                #pragma unroll
                for (int j = 0; j < 8; j++)
                    acc[i][j] = fmaf(xv[i], wv[j], acc[i][j]);
        }
    }

    #pragma unroll
    for (int j = 0; j < 8; j++) bv[j] = b2[gc*8 + j];

    float s[8], q[8];
    #pragma unroll
    for (int j = 0; j < 8; j++) { s[j] = 0.f; q[j] = 0.f; }
    #pragma unroll
    for (int i = 0; i < 8; i++) {
        const int n = base + gn*8 + i;
        if (n < N) {
            float h2[8];
            #pragma unroll
            for (int j = 0; j < 8; j++) h2[j] = acc[i][j] + bv[j];
            float4 va = {h2[0], h2[1], h2[2], h2[3]};
            float4 vb = {h2[4], h2[5], h2[6], h2[7]};
            float* op = out + (size_t)n * 128 + gc*8;
            *(float4*)op = va;
            *(float4*)(op + 4) = vb;
            #pragma unroll
            for (int j = 0; j < 8; j++) { s[j] += h2[j]; q[j] += h2[j]*h2[j]; }
        }
    }

    __syncthreads();
    float* RedS = Ws;
    float* RedQ = Ws + 2048;
    #pragma unroll
    for (int j = 0; j < 8; j++) {
        RedS[gn*128 + gc*8 + j] = s[j];
        RedQ[gn*128 + gc*8 + j] = q[j];
    }
    __syncthreads();
    if (tid < 128) {
        float ss = 0.f, qq = 0.f;
        #pragma unroll
        for (int g = 0; g < 16; g++) { ss += RedS[g*128 + tid]; qq += RedQ[g*128 + tid]; }
        unsafeAtomicAdd(&stats[tid], (double)ss);
        unsafeAtomicAdd(&stats[128 + tid], (double)qq);
    }
}

__global__ void bnprep_kernel(const double* __restrict__ stats, const float* __restrict__ gamma,
                              const float* __restrict__ beta, float* __restrict__ sb, float invN) {
    const int c = threadIdx.x;
    const float mean = (float)(stats[c] * (double)invN);
    const float ex2  = (float)(stats[128 + c] * (double)invN);
    const float var  = ex2 - mean * mean;
    const float rstd = rsqrtf(var + BN_EPS);
    const float sc = rstd * gamma[c];
    sb[c] = sc;
    sb[128 + c] = beta[c] - mean * sc;
}

__global__ void bn_kernel(float4* __restrict__ out4, const float* __restrict__ sb, int n4) {
    int i = blockIdx.x * blockDim.x + threadIdx.x;
    const int stride = gridDim.x * blockDim.x;
    for (; i < n4; i += stride) {
        const int c4 = (i & 31) << 2;
        float4 v = out4[i];
        const float4 sc = *(const float4*)&sb[c4];
        const float4 bs = *(const float4*)&sb[128 + c4];
        v.x = fmaxf(fmaf(v.x, sc.x, bs.x), 0.f);
        v.y = fmaxf(fmaf(v.y, sc.y, bs.y), 0.f);
        v.z = fmaxf(fmaf(v.z, sc.z, bs.z), 0.f);
        v.w = fmaxf(fmaf(v.w, sc.w, bs.w), 0.f);
        out4[i] = v;
    }
}

extern "C" void kernel_launch(void* const* d_in, const int* in_sizes, int n_in,
                              void* d_out, int out_size, void* d_ws, size_t ws_size,
                              hipStream_t stream) {
    const float* x     = (const float*)d_in[0];
    const int*   ei    = (const int*)d_in[1];
    const float* ea    = (const float*)d_in[2];
    const float* W1    = (const float*)d_in[3];
    const float* b1    = (const float*)d_in[4];
    const float* W2    = (const float*)d_in[5];
    const float* b2    = (const float*)d_in[6];
    const float* gamma = (const float*)d_in[7];
    const float* beta  = (const float*)d_in[8];
    float* out = (float*)d_out;

    const int N = in_sizes[0] / 128;
    const int E = in_sizes[1] / 2;

    // workspace layout
    char* w = (char*)d_ws;
    int* deg = (int*)w;
    size_t o = ((size_t)N * 4 + 7) & ~(size_t)7;
    const size_t zeroLen = o + 2048;               // deg + stats
    double* stats = (double*)(w + o); o += 2048;   // 256 doubles
    float*  sb    = (float*)(w + o);  o += 1024;   // 256 floats
    int* rowStart = (int*)(w + o);    o += (size_t)N * 4;
    int* cursor   = (int*)(w + o);    o += (size_t)N * 4;
    int* blockSums= (int*)(w + o);    o += 1024;
    int* sEid     = (int*)(w + o);    o += (size_t)E * 4;
    int* sSrc     = (int*)(w + o);

    hipMemsetAsync(d_ws, 0, zeroLen, stream);

    const int nblk = (N + 1023) / 1024;
    count_kernel<<<2048, 256, 0, stream>>>(ei, deg, E);
    scanA<<<nblk, 256, 0, stream>>>(deg, rowStart, blockSums, N);
    scanB<<<1, 256, 0, stream>>>(blockSums, nblk);
    scanC<<<256, 256, 0, stream>>>(rowStart, cursor, blockSums, N);
    scatter_kernel<<<2048, 256, 0, stream>>>(ei, cursor, sEid, sSrc, E);

    // h0 = x + aggregate, written into d_out (MLP reads & overwrites in-place per tile)
    agg_kernel<<<(N * 64 + 255) / 256, 256, 0, stream>>>(x, ea, sEid, sSrc, rowStart, deg, out, N);

    mlp_kernel<<<(N + 127) / 128, 256, 0, stream>>>(out, W1, b1, W2, b2, out, stats, N);

    bnprep_kernel<<<1, 128, 0, stream>>>(stats, gamma, beta, sb, 1.0f / (float)N);

    bn_kernel<<<2048, 256, 0, stream>>>((float4*)out, sb, N * 32);
}